// Round 1
// baseline (1614.877 us; speedup 1.0000x reference)
//
#include <hip/hip_runtime.h>
#include <hip/hip_bf16.h>

#define CDIV(a,b) (((a)+(b)-1)/(b))

// ---------------------------------------------------------------- CSR build
__global__ void k_deg(const int* __restrict__ dst, int E, int* __restrict__ deg){
    int i = blockIdx.x*blockDim.x + threadIdx.x;
    if (i < E) atomicAdd(&deg[dst[i]], 1);
}

__global__ void k_scan1(const int* __restrict__ deg, int N,
                        int* __restrict__ row_ptr, int* __restrict__ bsum){
    __shared__ int s[1024];
    int t = threadIdx.x;
    int i = blockIdx.x*1024 + t;
    int v = (i < N) ? deg[i] : 0;
    s[t] = v;
    __syncthreads();
    for (int off = 1; off < 1024; off <<= 1){
        int x = (t >= off) ? s[t-off] : 0;
        __syncthreads();
        s[t] += x;
        __syncthreads();
    }
    if (i < N) row_ptr[i] = s[t];              // inclusive local scan
    if (t == 1023) bsum[blockIdx.x] = s[1023]; // block total
}

__global__ void k_scan2(int* __restrict__ bsum, int B){
    if (threadIdx.x == 0){
        int acc = 0;
        for (int i = 0; i < B; ++i){ int v = bsum[i]; bsum[i] = acc; acc += v; }
    }
}

__global__ void k_scan3(const int* __restrict__ deg, const int* __restrict__ bsum,
                        int N, int E, int* __restrict__ row_ptr,
                        int* __restrict__ cursor, float* __restrict__ inv_deg){
    int i = blockIdx.x*1024 + threadIdx.x;
    if (i == 0) row_ptr[N] = E;
    if (i < N){
        int d  = deg[i];
        int rp = row_ptr[i] - d + bsum[blockIdx.x]; // exclusive global scan
        row_ptr[i] = rp;
        cursor[i]  = rp;
        inv_deg[i] = 1.0f / (float)(d > 1 ? d : 1);
    }
}

__global__ void k_fill(const int* __restrict__ src, const int* __restrict__ dst,
                       int E, int* __restrict__ cursor, int* __restrict__ col_idx){
    int i = blockIdx.x*blockDim.x + threadIdx.x;
    if (i < E){
        int p = atomicAdd(&cursor[dst[i]], 1);
        col_idx[p] = src[i];
    }
}

// ---------------------------------------------------------------- aggregation
// one wave (64 lanes) per node; float2 per lane covers 128 cols
__global__ __launch_bounds__(256) void k_agg(
    const float* __restrict__ h, const int* __restrict__ row_ptr,
    const int* __restrict__ col_idx, const float* __restrict__ inv_deg,
    float* __restrict__ agg, int N)
{
    int wave = (blockIdx.x*blockDim.x + threadIdx.x) >> 6;
    int lane = threadIdx.x & 63;
    if (wave >= N) return;
    int beg = row_ptr[wave], end = row_ptr[wave+1];
    float2 a = make_float2(0.f, 0.f);
    for (int j = beg; j < end; ++j){
        int s = col_idx[j];
        float2 v = reinterpret_cast<const float2*>(h + (size_t)s*128)[lane];
        a.x += v.x; a.y += v.y;
    }
    float sc = inv_deg[wave];
    a.x *= sc; a.y *= sc;
    reinterpret_cast<float2*>(agg + (size_t)wave*128)[lane] = a;
}

// ---------------------------------------------------------------- GEMM, C=128
// out[N,128] = sum_p A_p[N,128] @ W_p[128,128]  + bias
// block: 256 thr, tile 128 rows x 128 cols, 8x8 micro-tile
__global__ __launch_bounds__(256) void k_gemm128(
    const float* __restrict__ A0, const float* __restrict__ Wm0,
    const float* __restrict__ A1, const float* __restrict__ Wm1,
    const float* __restrict__ A2, const float* __restrict__ Wm2,
    const float* __restrict__ A3, const float* __restrict__ Wm3,
    int P, const float* __restrict__ bias, float* __restrict__ out, int N)
{
    __shared__ float As[128][65];   // rows x k-chunk(64), +1 pad
    __shared__ float Ws[64][132];   // k-chunk x cols(128), +4 pad
    const int t  = threadIdx.x;
    const int tx = t & 15, ty = t >> 4;
    const int r0 = blockIdx.x * 128;

    float acc[8][8];
    #pragma unroll
    for (int i = 0; i < 8; ++i)
        #pragma unroll
        for (int j = 0; j < 8; ++j) acc[i][j] = 0.f;

    for (int p = 0; p < P; ++p){
        const float* A = (p==0) ? A0 : (p==1) ? A1 : (p==2) ? A2 : A3;
        const float* W = (p==0) ? Wm0: (p==1) ? Wm1: (p==2) ? Wm2: Wm3;
        for (int kc = 0; kc < 128; kc += 64){
            // stage A chunk: 128 rows x 64 k
            #pragma unroll
            for (int q = 0; q < 8; ++q){
                int f   = q*256 + t;
                int row = f >> 4, c4 = (f & 15) * 4;
                int gr  = r0 + row;
                float4 v = make_float4(0.f,0.f,0.f,0.f);
                if (gr < N) v = *reinterpret_cast<const float4*>(A + (size_t)gr*128 + kc + c4);
                As[row][c4+0]=v.x; As[row][c4+1]=v.y; As[row][c4+2]=v.z; As[row][c4+3]=v.w;
            }
            // stage W chunk: 64 k x 128 cols
            #pragma unroll
            for (int q = 0; q < 8; ++q){
                int f  = q*256 + t;
                int kk = f >> 5, c4 = (f & 31) * 4;
                float4 v = *reinterpret_cast<const float4*>(W + (size_t)(kc+kk)*128 + c4);
                Ws[kk][c4+0]=v.x; Ws[kk][c4+1]=v.y; Ws[kk][c4+2]=v.z; Ws[kk][c4+3]=v.w;
            }
            __syncthreads();
            #pragma unroll 4
            for (int kk = 0; kk < 64; ++kk){
                float a[8], w[8];
                #pragma unroll
                for (int i = 0; i < 8; ++i) a[i] = As[ty*8+i][kk];
                #pragma unroll
                for (int j = 0; j < 8; ++j) w[j] = Ws[kk][tx*8+j];
                #pragma unroll
                for (int i = 0; i < 8; ++i)
                    #pragma unroll
                    for (int j = 0; j < 8; ++j) acc[i][j] += a[i]*w[j];
            }
            __syncthreads();
        }
    }
    // epilogue: + bias, store
    float b[8];
    #pragma unroll
    for (int j = 0; j < 8; ++j) b[j] = bias[tx*8+j];
    #pragma unroll
    for (int i = 0; i < 8; ++i){
        int r = r0 + ty*8 + i;
        if (r < N){
            float4 v0 = make_float4(acc[i][0]+b[0], acc[i][1]+b[1], acc[i][2]+b[2], acc[i][3]+b[3]);
            float4 v1 = make_float4(acc[i][4]+b[4], acc[i][5]+b[5], acc[i][6]+b[6], acc[i][7]+b[7]);
            *reinterpret_cast<float4*>(out + (size_t)r*128 + tx*8    ) = v0;
            *reinterpret_cast<float4*>(out + (size_t)r*128 + tx*8 + 4) = v1;
        }
    }
}

// ---------------------------------------------------------------- GEMM out, C=64
// out[N,64] = A[N,128] @ W[128,64] + bias ; tile 64 rows, 4x4 micro
__global__ __launch_bounds__(256) void k_gemm_out(
    const float* __restrict__ A, const float* __restrict__ W,
    const float* __restrict__ bias, float* __restrict__ out, int N)
{
    __shared__ float As[64][129];
    __shared__ float Ws[128][68];
    const int t  = threadIdx.x;
    const int tx = t & 15, ty = t >> 4;
    const int r0 = blockIdx.x * 64;

    // stage A tile 64x128
    #pragma unroll
    for (int q = 0; q < 8; ++q){
        int f   = q*256 + t;
        int row = f >> 5, c4 = (f & 31) * 4;
        int gr  = r0 + row;
        float4 v = make_float4(0.f,0.f,0.f,0.f);
        if (gr < N) v = *reinterpret_cast<const float4*>(A + (size_t)gr*128 + c4);
        As[row][c4+0]=v.x; As[row][c4+1]=v.y; As[row][c4+2]=v.z; As[row][c4+3]=v.w;
    }
    // stage W 128x64
    #pragma unroll
    for (int q = 0; q < 8; ++q){
        int f  = q*256 + t;
        int kk = f >> 4, c4 = (f & 15) * 4;
        float4 v = *reinterpret_cast<const float4*>(W + (size_t)kk*64 + c4);
        Ws[kk][c4+0]=v.x; Ws[kk][c4+1]=v.y; Ws[kk][c4+2]=v.z; Ws[kk][c4+3]=v.w;
    }
    __syncthreads();

    float acc[4][4];
    #pragma unroll
    for (int i = 0; i < 4; ++i)
        #pragma unroll
        for (int j = 0; j < 4; ++j) acc[i][j] = 0.f;

    #pragma unroll 4
    for (int k = 0; k < 128; ++k){
        float a[4];
        #pragma unroll
        for (int i = 0; i < 4; ++i) a[i] = As[ty*4+i][k];
        float w0 = Ws[k][tx*4+0], w1 = Ws[k][tx*4+1], w2 = Ws[k][tx*4+2], w3 = Ws[k][tx*4+3];
        #pragma unroll
        for (int i = 0; i < 4; ++i){
            acc[i][0] += a[i]*w0; acc[i][1] += a[i]*w1;
            acc[i][2] += a[i]*w2; acc[i][3] += a[i]*w3;
        }
    }
    float b0 = bias[tx*4+0], b1 = bias[tx*4+1], b2 = bias[tx*4+2], b3 = bias[tx*4+3];
    #pragma unroll
    for (int i = 0; i < 4; ++i){
        int r = r0 + ty*4 + i;
        if (r < N){
            float4 v = make_float4(acc[i][0]+b0, acc[i][1]+b1, acc[i][2]+b2, acc[i][3]+b3);
            *reinterpret_cast<float4*>(out + (size_t)r*64 + tx*4) = v;
        }
    }
}

// ---------------------------------------------------------------- batchnorm
__global__ __launch_bounds__(128) void k_colstats(
    const float* __restrict__ h, int N, float* __restrict__ stats)
{
    int c = threadIdx.x; // 128 cols
    float s1 = 0.f, s2 = 0.f;
    for (int r = blockIdx.x; r < N; r += gridDim.x){
        float v = h[(size_t)r*128 + c];
        s1 += v; s2 += v*v;
    }
    atomicAdd(&stats[c], s1);
    atomicAdd(&stats[128+c], s2);
}

__global__ void k_bnparams(const float* __restrict__ stats,
                           const float* __restrict__ gamma, const float* __restrict__ beta,
                           int N, float* __restrict__ ss)
{
    int c = threadIdx.x;
    if (c < 128){
        float m  = stats[c] / (float)N;
        float v  = stats[128+c] / (float)N - m*m;
        float is = rsqrtf(v + 1e-5f);
        float sc = is * gamma[c];
        ss[c]      = sc;
        ss[128+c]  = beta[c] - m*sc;
    }
}

template<int LEAKY>
__global__ __launch_bounds__(256) void k_norm_act(
    const float* __restrict__ pre, const float* __restrict__ ss,
    float* __restrict__ out, int total4)
{
    int i = blockIdx.x*blockDim.x + threadIdx.x;
    if (i >= total4) return;
    float4 v = reinterpret_cast<const float4*>(pre)[i];
    int c = (i & 31) * 4;  // 128 cols = 32 float4 per row
    v.x = v.x*ss[c+0] + ss[128+c+0];
    v.y = v.y*ss[c+1] + ss[128+c+1];
    v.z = v.z*ss[c+2] + ss[128+c+2];
    v.w = v.w*ss[c+3] + ss[128+c+3];
    if (LEAKY){
        v.x = v.x > 0.f ? v.x : 0.01f*v.x;
        v.y = v.y > 0.f ? v.y : 0.01f*v.y;
        v.z = v.z > 0.f ? v.z : 0.01f*v.z;
        v.w = v.w > 0.f ? v.w : 0.01f*v.w;
    } else {
        v.x = fmaxf(v.x, 0.f); v.y = fmaxf(v.y, 0.f);
        v.z = fmaxf(v.z, 0.f); v.w = fmaxf(v.w, 0.f);
    }
    reinterpret_cast<float4*>(out)[i] = v;
}

// ---------------------------------------------------------------- launch
extern "C" void kernel_launch(void* const* d_in, const int* in_sizes, int n_in,
                              void* d_out, int out_size, void* d_ws, size_t ws_size,
                              hipStream_t stream)
{
    const float* x     = (const float*)d_in[0];
    const int*   ei    = (const int*)  d_in[1];
    const float* Wl    = (const float*)d_in[2];
    const float* bl    = (const float*)d_in[3];
    const float* Wr    = (const float*)d_in[4];
    const float* gamma = (const float*)d_in[5];
    const float* beta  = (const float*)d_in[6];
    const float* W1    = (const float*)d_in[7];
    const float* b1    = (const float*)d_in[8];
    const float* g1    = (const float*)d_in[9];
    const float* be1   = (const float*)d_in[10];
    const float* W2    = (const float*)d_in[11];
    const float* b2    = (const float*)d_in[12];
    float* out = (float*)d_out;

    const int N = in_sizes[0] / 128;
    const int E = in_sizes[1] / 2;
    const int*   src = ei;
    const int*   dst = ei + E;

    // workspace carve
    char* w = (char*)d_ws;
    const size_t S = (size_t)N * 128 * sizeof(float);
    float* hb0  = (float*)(w + 0*S);
    float* hb1  = (float*)(w + 1*S);
    float* hb2  = (float*)(w + 2*S);
    float* agg  = (float*)(w + 3*S);
    float* pre  = (float*)(w + 4*S);
    char*  p    = w + 5*S;
    int*   col_idx = (int*)p;            p += (size_t)E*4;
    int*   row_ptr = (int*)p;            p += (size_t)(N+1)*4;
    int*   cursor  = (int*)p;            p += (size_t)N*4;
    int*   deg     = (int*)p;            p += (size_t)N*4;
    float* inv_deg = (float*)p;          p += (size_t)N*4;
    int*   bsum    = (int*)p;            p += 1024*4;
    float* stats   = (float*)p;          p += 256*4;
    float* ssbuf   = (float*)p;          p += 256*4;

    const int SCAN_B = CDIV(N, 1024);

    // ---- CSR build
    hipMemsetAsync(deg, 0, (size_t)N*4, stream);
    k_deg<<<CDIV(E,256), 256, 0, stream>>>(dst, E, deg);
    k_scan1<<<SCAN_B, 1024, 0, stream>>>(deg, N, row_ptr, bsum);
    k_scan2<<<1, 64, 0, stream>>>(bsum, SCAN_B);
    k_scan3<<<SCAN_B, 1024, 0, stream>>>(deg, bsum, N, E, row_ptr, cursor, inv_deg);
    k_fill<<<CDIV(E,256), 256, 0, stream>>>(src, dst, E, cursor, col_idx);

    const int total4 = N * 32;
    float* hbuf[3] = {hb0, hb1, hb2};

    // ---- 3 SAGE layers
    const float* h = x;
    for (int L = 0; L < 3; ++L){
        k_agg<<<CDIV(N,4), 256, 0, stream>>>(h, row_ptr, col_idx, inv_deg, agg, N);
        k_gemm128<<<CDIV(N,128), 256, 0, stream>>>(
            agg, Wl + (size_t)L*128*128,
            h,   Wr + (size_t)L*128*128,
            nullptr, nullptr, nullptr, nullptr,
            2, bl + (size_t)L*128, pre, N);
        hipMemsetAsync(stats, 0, 256*4, stream);
        k_colstats<<<1024, 128, 0, stream>>>(pre, N, stats);
        k_bnparams<<<1, 128, 0, stream>>>(stats, gamma + (size_t)L*128, beta + (size_t)L*128, N, ssbuf);
        k_norm_act<0><<<CDIV(total4,256), 256, 0, stream>>>(pre, ssbuf, hbuf[L], total4);
        h = hbuf[L];
    }

    // ---- head: z = [x,h1,h2,h3] @ W1 (+b1) -> BN -> leaky -> @ W2 (+b2)
    k_gemm128<<<CDIV(N,128), 256, 0, stream>>>(
        x,   W1 + 0,
        hb0, W1 + (size_t)128*128,
        hb1, W1 + (size_t)256*128,
        hb2, W1 + (size_t)384*128,
        4, b1, pre, N);
    hipMemsetAsync(stats, 0, 256*4, stream);
    k_colstats<<<1024, 128, 0, stream>>>(pre, N, stats);
    k_bnparams<<<1, 128, 0, stream>>>(stats, g1, be1, N, ssbuf);
    k_norm_act<1><<<CDIV(total4,256), 256, 0, stream>>>(pre, ssbuf, agg, total4);

    k_gemm_out<<<CDIV(N,64), 256, 0, stream>>>(agg, W2, b2, out, N);
}

// Round 2
// 934.145 us; speedup vs baseline: 1.7287x; 1.7287x over previous
//
#include <hip/hip_runtime.h>
#include <hip/hip_bf16.h>

#define CDIV(a,b) (((a)+(b)-1)/(b))

typedef __attribute__((ext_vector_type(8))) short short8_t;
typedef __attribute__((ext_vector_type(4))) float f32x4;

__device__ __forceinline__ float b2f(ushort u){
    union { uint i; float f; } v; v.i = ((uint)u) << 16; return v.f;
}
__device__ __forceinline__ ushort f2b(float f){
    __hip_bfloat16 h = __float2bfloat16(f);
    return *reinterpret_cast<ushort*>(&h);
}

// ---------------------------------------------------------------- CSR build
__global__ void k_deg(const int* __restrict__ dst, int E, int* __restrict__ deg){
    int i = blockIdx.x*blockDim.x + threadIdx.x;
    if (i < E) atomicAdd(&deg[dst[i]], 1);
}

__global__ void k_scan1(const int* __restrict__ deg, int N,
                        int* __restrict__ row_ptr, int* __restrict__ bsum){
    __shared__ int s[1024];
    int t = threadIdx.x;
    int i = blockIdx.x*1024 + t;
    int v = (i < N) ? deg[i] : 0;
    s[t] = v;
    __syncthreads();
    for (int off = 1; off < 1024; off <<= 1){
        int x = (t >= off) ? s[t-off] : 0;
        __syncthreads();
        s[t] += x;
        __syncthreads();
    }
    if (i < N) row_ptr[i] = s[t];
    if (t == 1023) bsum[blockIdx.x] = s[1023];
}

__global__ void k_scan2(int* __restrict__ bsum, int B){
    if (threadIdx.x == 0){
        int acc = 0;
        for (int i = 0; i < B; ++i){ int v = bsum[i]; bsum[i] = acc; acc += v; }
    }
}

__global__ void k_scan3(const int* __restrict__ deg, const int* __restrict__ bsum,
                        int N, int E, int* __restrict__ row_ptr,
                        int* __restrict__ cursor, float* __restrict__ inv_deg){
    int i = blockIdx.x*1024 + threadIdx.x;
    if (i == 0) row_ptr[N] = E;
    if (i < N){
        int d  = deg[i];
        int rp = row_ptr[i] - d + bsum[blockIdx.x];
        row_ptr[i] = rp;
        cursor[i]  = rp;
        inv_deg[i] = 1.0f / (float)(d > 1 ? d : 1);
    }
}

__global__ void k_fill(const int* __restrict__ src, const int* __restrict__ dst,
                       int E, int* __restrict__ cursor, int* __restrict__ col_idx){
    int i = blockIdx.x*blockDim.x + threadIdx.x;
    if (i < E){
        int p = atomicAdd(&cursor[dst[i]], 1);
        col_idx[p] = src[i];
    }
}

// ---------------------------------------------------------------- conversions
__global__ void k_cvt_x(const float* __restrict__ in, ushort* __restrict__ out, int n4){
    int i = blockIdx.x*blockDim.x + threadIdx.x;
    if (i >= n4) return;
    float4 v = reinterpret_cast<const float4*>(in)[i];
    ushort4 o; o.x=f2b(v.x); o.y=f2b(v.y); o.z=f2b(v.z); o.w=f2b(v.w);
    reinterpret_cast<ushort4*>(out)[i] = o;
}

// in: [nslab][K][C] f32 -> out: [nslab][C][K] bf16 (transposed per slab)
__global__ void k_cvt_t(const float* __restrict__ in, ushort* __restrict__ out,
                        int K, int C, int total){
    int i = blockIdx.x*blockDim.x + threadIdx.x;
    if (i >= total) return;
    int kc = K*C;
    int s = i / kc, r = i - s*kc;
    int k = r / C, c = r - k*C;
    out[s*kc + c*K + k] = f2b(in[i]);
}

// ---------------------------------------------------------------- aggregation (bf16)
__global__ __launch_bounds__(256) void k_agg_bf(
    const ushort* __restrict__ h, const int* __restrict__ row_ptr,
    const int* __restrict__ col_idx, const float* __restrict__ inv_deg,
    ushort* __restrict__ agg, int N)
{
    int node = (blockIdx.x*blockDim.x + threadIdx.x) >> 6;
    int lane = threadIdx.x & 63;
    if (node >= N) return;
    int beg = row_ptr[node], end = row_ptr[node+1];
    float a0 = 0.f, a1 = 0.f;
    for (int j = beg; j < end; ++j){
        int s = col_idx[j];
        uint v = *reinterpret_cast<const uint*>(h + (size_t)s*128 + lane*2);
        a0 += b2f((ushort)(v & 0xffffu));
        a1 += b2f((ushort)(v >> 16));
    }
    float sc = inv_deg[node];
    uint o = (uint)f2b(a0*sc) | ((uint)f2b(a1*sc) << 16);
    *reinterpret_cast<uint*>(agg + (size_t)node*128 + lane*2) = o;
}

// ---------------------------------------------------------------- MFMA GEMM
// out[N, NCF*16] = sum_p A_p[N,128](bf16) @ T_p[NCF*16][128]^T(bf16) + bias
// block: 256 thr = 4 waves, 128 rows/block (32 rows/wave), all NCF*16 cols.
// T_p is the transposed weight [n][k], k-contiguous. LDS XOR-swizzled (T2).
template<int NCF, int STATS, int OUTBF>
__global__ __launch_bounds__(256) void k_gemm_mfma(
    const ushort* __restrict__ A0, const ushort* __restrict__ T0,
    const ushort* __restrict__ A1, const ushort* __restrict__ T1,
    const ushort* __restrict__ A2, const ushort* __restrict__ T2,
    const ushort* __restrict__ A3, const ushort* __restrict__ T3,
    int P, const float* __restrict__ bias,
    ushort* __restrict__ out_bf, float* __restrict__ out_f32,
    float* __restrict__ partials, int N)
{
    __shared__ ushort Ws[NCF*16*128];
    const int t   = threadIdx.x;
    const int w   = t >> 6, l = t & 63;
    const int l15 = l & 15, lg = l >> 4;
    const int r0   = blockIdx.x * 128;
    const int wrow = w * 32;

    f32x4 acc[2][NCF];
    #pragma unroll
    for (int i = 0; i < 2; ++i)
        #pragma unroll
        for (int j = 0; j < NCF; ++j) acc[i][j] = (f32x4){0.f,0.f,0.f,0.f};

    for (int p = 0; p < P; ++p){
        const ushort* A = (p==0)?A0:(p==1)?A1:(p==2)?A2:A3;
        const ushort* T = (p==0)?T0:(p==1)?T1:(p==2)?T2:T3;
        if (p) __syncthreads();
        // stage weights: NCF*16 rows x 128 k, 16B chunks, XOR swizzle c16 ^= row&7
        #pragma unroll
        for (int q = 0; q < NCF; ++q){
            int lin  = q*256 + t;
            int row  = lin >> 4, c16 = lin & 15;
            int c16s = c16 ^ (row & 7);
            uint4 v = *reinterpret_cast<const uint4*>(T + (size_t)row*128 + c16*8);
            *reinterpret_cast<uint4*>(&Ws[row*128 + c16s*8]) = v;
        }
        __syncthreads();
        #pragma unroll
        for (int kk = 0; kk < 4; ++kk){
            const int k0 = kk*32;
            short8_t a[2];
            #pragma unroll
            for (int rf = 0; rf < 2; ++rf){
                size_t gr = (size_t)(r0 + wrow + rf*16 + l15);
                a[rf] = *reinterpret_cast<const short8_t*>(A + gr*128 + k0 + lg*8);
            }
            #pragma unroll
            for (int cf = 0; cf < NCF; ++cf){
                int row  = cf*16 + l15;
                int c16  = (k0 >> 3) + lg;
                int c16s = c16 ^ (row & 7);
                short8_t b = *reinterpret_cast<const short8_t*>(&Ws[row*128 + c16s*8]);
                acc[0][cf] = __builtin_amdgcn_mfma_f32_16x16x32_bf16(a[0], b, acc[0][cf], 0, 0, 0);
                acc[1][cf] = __builtin_amdgcn_mfma_f32_16x16x32_bf16(a[1], b, acc[1][cf], 0, 0, 0);
            }
        }
    }

    // epilogue: +bias, (optional stats partials), store
    float bs[NCF];
    #pragma unroll
    for (int cf = 0; cf < NCF; ++cf) bs[cf] = bias[cf*16 + l15];

    float s1[NCF], s2[NCF];
    #pragma unroll
    for (int cf = 0; cf < NCF; ++cf){ s1[cf] = 0.f; s2[cf] = 0.f; }

    #pragma unroll
    for (int rf = 0; rf < 2; ++rf){
        #pragma unroll
        for (int q = 0; q < 4; ++q){
            int gr = r0 + wrow + rf*16 + lg*4 + q;
            bool valid = gr < N;
            #pragma unroll
            for (int cf = 0; cf < NCF; ++cf){
                float v = acc[rf][cf][q] + bs[cf];
                if (valid){
                    if (STATS){ s1[cf] += v; s2[cf] += v*v; }
                    int col = cf*16 + l15;
                    if (OUTBF) out_bf[(size_t)gr*(NCF*16) + col] = f2b(v);
                    else       out_f32[(size_t)gr*(NCF*16) + col] = v;
                }
            }
        }
    }
    if (STATS){
        #pragma unroll
        for (int cf = 0; cf < NCF; ++cf){
            s1[cf] += __shfl_xor(s1[cf], 16);
            s1[cf] += __shfl_xor(s1[cf], 32);
            s2[cf] += __shfl_xor(s2[cf], 16);
            s2[cf] += __shfl_xor(s2[cf], 32);
        }
        if (l < 16){
            float* pb = partials + (size_t)(blockIdx.x*4 + w)*256;
            #pragma unroll
            for (int cf = 0; cf < NCF; ++cf){
                pb[cf*16 + l15]       = s1[cf];
                pb[128 + cf*16 + l15] = s2[cf];
            }
        }
    }
}

// ---------------------------------------------------------------- BN reduce
// partials: [I][256] (s1[128] | s2[128]) -> ss: scale[128] | shift[128]
__global__ void k_bnreduce(const float* __restrict__ partials, int I, int N,
                           const float* __restrict__ gamma, const float* __restrict__ beta,
                           float* __restrict__ ss)
{
    int c = blockIdx.x;   // 0..127
    int l = threadIdx.x;  // 64
    float s1 = 0.f, s2 = 0.f;
    for (int i = l; i < I; i += 64){
        s1 += partials[(size_t)i*256 + c];
        s2 += partials[(size_t)i*256 + 128 + c];
    }
    #pragma unroll
    for (int off = 32; off; off >>= 1){
        s1 += __shfl_xor(s1, off);
        s2 += __shfl_xor(s2, off);
    }
    if (l == 0){
        float m   = s1 / (float)N;
        float var = s2 / (float)N - m*m;
        float sc  = rsqrtf(var + 1e-5f) * gamma[c];
        ss[c]     = sc;
        ss[128+c] = beta[c] - m*sc;
    }
}

// ---------------------------------------------------------------- norm + act (bf16)
template<int LEAKY>
__global__ __launch_bounds__(256) void k_norm_act_bf(
    const ushort* __restrict__ pre, const float* __restrict__ ss,
    ushort* __restrict__ out, int total8)
{
    int i = blockIdx.x*blockDim.x + threadIdx.x;
    if (i >= total8) return;
    uint4 v = reinterpret_cast<const uint4*>(pre)[i];
    int c0 = (i & 15) * 8;
    uint vv[4] = {v.x, v.y, v.z, v.w};
    uint r[4];
    #pragma unroll
    for (int q = 0; q < 4; ++q){
        float f0 = b2f((ushort)(vv[q] & 0xffffu)) * ss[c0+q*2]   + ss[128+c0+q*2];
        float f1 = b2f((ushort)(vv[q] >> 16))     * ss[c0+q*2+1] + ss[128+c0+q*2+1];
        if (LEAKY){ f0 = f0 > 0.f ? f0 : 0.01f*f0; f1 = f1 > 0.f ? f1 : 0.01f*f1; }
        else      { f0 = fmaxf(f0, 0.f); f1 = fmaxf(f1, 0.f); }
        r[q] = (uint)f2b(f0) | ((uint)f2b(f1) << 16);
    }
    reinterpret_cast<uint4*>(out)[i] = make_uint4(r[0], r[1], r[2], r[3]);
}

// ---------------------------------------------------------------- launch
extern "C" void kernel_launch(void* const* d_in, const int* in_sizes, int n_in,
                              void* d_out, int out_size, void* d_ws, size_t ws_size,
                              hipStream_t stream)
{
    const float* x     = (const float*)d_in[0];
    const int*   ei    = (const int*)  d_in[1];
    const float* Wl    = (const float*)d_in[2];
    const float* bl    = (const float*)d_in[3];
    const float* Wr    = (const float*)d_in[4];
    const float* gamma = (const float*)d_in[5];
    const float* beta  = (const float*)d_in[6];
    const float* W1    = (const float*)d_in[7];
    const float* b1    = (const float*)d_in[8];
    const float* g1    = (const float*)d_in[9];
    const float* be1   = (const float*)d_in[10];
    const float* W2    = (const float*)d_in[11];
    const float* b2    = (const float*)d_in[12];
    float* out = (float*)d_out;

    const int N  = in_sizes[0] / 128;
    const int E  = in_sizes[1] / 2;
    const int NB = CDIV(N, 128);
    const size_t NPAD = (size_t)NB * 128;
    const int* src = ei;
    const int* dst = ei + E;

    // workspace carve
    char* w = (char*)d_ws;
    const size_t SB = NPAD * 128 * sizeof(ushort);   // bf16 activation slab
    ushort* x_bf = (ushort*)(w + 0*SB);
    ushort* h0   = (ushort*)(w + 1*SB);
    ushort* h1   = (ushort*)(w + 2*SB);
    ushort* h2   = (ushort*)(w + 3*SB);
    ushort* aggb = (ushort*)(w + 4*SB);
    ushort* preb = (ushort*)(w + 5*SB);
    char* p = w + 6*SB;
    ushort* WtL = (ushort*)p;  p += (size_t)3*16384*2;
    ushort* WtR = (ushort*)p;  p += (size_t)3*16384*2;
    ushort* Wt1 = (ushort*)p;  p += (size_t)4*16384*2;
    ushort* Wt2 = (ushort*)p;  p += (size_t)8192*2;
    float* partials = (float*)p; p += (size_t)NB*4*256*sizeof(float);
    int*   col_idx  = (int*)p;   p += (size_t)E*4;
    int*   row_ptr  = (int*)p;   p += (size_t)(N+1)*4;
    int*   cursor   = (int*)p;   p += (size_t)N*4;
    int*   deg      = (int*)p;   p += (size_t)N*4;
    float* inv_deg  = (float*)p; p += (size_t)N*4;
    int*   bsum     = (int*)p;   p += 1024*4;
    float* ssb      = (float*)p; p += 256*4;

    const int SCAN_B = CDIV(N, 1024);

    // conversions
    const int n4 = N * 32;
    k_cvt_x<<<CDIV(n4,256), 256, 0, stream>>>(x, x_bf, n4);
    k_cvt_t<<<CDIV(3*16384,256), 256, 0, stream>>>(Wl, WtL, 128, 128, 3*16384);
    k_cvt_t<<<CDIV(3*16384,256), 256, 0, stream>>>(Wr, WtR, 128, 128, 3*16384);
    k_cvt_t<<<CDIV(4*16384,256), 256, 0, stream>>>(W1, Wt1, 128, 128, 4*16384);
    k_cvt_t<<<CDIV(8192,256),    256, 0, stream>>>(W2, Wt2, 128,  64, 8192);

    // CSR build
    hipMemsetAsync(deg, 0, (size_t)N*4, stream);
    k_deg<<<CDIV(E,256), 256, 0, stream>>>(dst, E, deg);
    k_scan1<<<SCAN_B, 1024, 0, stream>>>(deg, N, row_ptr, bsum);
    k_scan2<<<1, 64, 0, stream>>>(bsum, SCAN_B);
    k_scan3<<<SCAN_B, 1024, 0, stream>>>(deg, bsum, N, E, row_ptr, cursor, inv_deg);
    k_fill<<<CDIV(E,256), 256, 0, stream>>>(src, dst, E, cursor, col_idx);

    // 3 SAGE layers
    const ushort* h = x_bf;
    ushort* hb[3] = {h0, h1, h2};
    const int total8 = N * 16;
    for (int L = 0; L < 3; ++L){
        k_agg_bf<<<CDIV(N,4), 256, 0, stream>>>(h, row_ptr, col_idx, inv_deg, aggb, N);
        k_gemm_mfma<8,1,1><<<NB, 256, 0, stream>>>(
            aggb, WtL + (size_t)L*16384,
            h,    WtR + (size_t)L*16384,
            nullptr, nullptr, nullptr, nullptr,
            2, bl + (size_t)L*128, preb, nullptr, partials, N);
        k_bnreduce<<<128, 64, 0, stream>>>(partials, NB*4, N,
            gamma + (size_t)L*128, beta + (size_t)L*128, ssb);
        k_norm_act_bf<0><<<CDIV(total8,256), 256, 0, stream>>>(preb, ssb, hb[L], total8);
        h = hb[L];
    }

    // head: z = [x,h1,h2,h3] @ W1 + b1 -> BN -> leaky
    k_gemm_mfma<8,1,1><<<NB, 256, 0, stream>>>(
        x_bf, Wt1 + 0,
        h0,   Wt1 + 16384,
        h1,   Wt1 + 2*16384,
        h2,   Wt1 + 3*16384,
        4, b1, preb, nullptr, partials, N);
    k_bnreduce<<<128, 64, 0, stream>>>(partials, NB*4, N, g1, be1, ssb);
    k_norm_act_bf<1><<<CDIV(total8,256), 256, 0, stream>>>(preb, ssb, aggb, total8);

    // out: [N,128] @ W2 + b2 -> f32 d_out
    k_gemm_mfma<4,0,0><<<NB, 256, 0, stream>>>(
        aggb, Wt2, nullptr, nullptr, nullptr, nullptr, nullptr, nullptr,
        1, b2, nullptr, out, nullptr, N);
}

// Round 3
// 661.579 us; speedup vs baseline: 2.4409x; 1.4120x over previous
//
#include <hip/hip_runtime.h>
#include <hip/hip_bf16.h>

#define CDIV(a,b) (((a)+(b)-1)/(b))

typedef __attribute__((ext_vector_type(8))) short short8_t;
typedef __attribute__((ext_vector_type(4))) float f32x4;

__device__ __forceinline__ float b2f(ushort u){
    union { uint i; float f; } v; v.i = ((uint)u) << 16; return v.f;
}
__device__ __forceinline__ ushort f2b(float f){
    __hip_bfloat16 h = __float2bfloat16(f);
    return *reinterpret_cast<ushort*>(&h);
}

// ---------------------------------------------------------------- CSR build
__global__ void k_deg(const int* __restrict__ dst, int E, int* __restrict__ deg){
    int i = blockIdx.x*blockDim.x + threadIdx.x;
    if (i < E) atomicAdd(&deg[dst[i]], 1);
}

__global__ void k_scan1(const int* __restrict__ deg, int N,
                        int* __restrict__ row_ptr, int* __restrict__ bsum){
    __shared__ int s[1024];
    int t = threadIdx.x;
    int i = blockIdx.x*1024 + t;
    int v = (i < N) ? deg[i] : 0;
    s[t] = v;
    __syncthreads();
    for (int off = 1; off < 1024; off <<= 1){
        int x = (t >= off) ? s[t-off] : 0;
        __syncthreads();
        s[t] += x;
        __syncthreads();
    }
    if (i < N) row_ptr[i] = s[t];
    if (t == 1023) bsum[blockIdx.x] = s[1023];
}

// parallel exclusive scan over B (<=1024) block sums, one block
__global__ void k_scan2(int* __restrict__ bsum, int B){
    __shared__ int s[1024];
    int t = threadIdx.x;
    int v = (t < B) ? bsum[t] : 0;
    s[t] = v;
    __syncthreads();
    for (int off = 1; off < 1024; off <<= 1){
        int x = (t >= off) ? s[t-off] : 0;
        __syncthreads();
        s[t] += x;
        __syncthreads();
    }
    if (t < B) bsum[t] = s[t] - v;  // exclusive
}

__global__ void k_scan3(const int* __restrict__ deg, const int* __restrict__ bsum,
                        int N, int E, int* __restrict__ row_ptr,
                        int* __restrict__ cursor, float* __restrict__ inv_deg){
    int i = blockIdx.x*1024 + threadIdx.x;
    if (i == 0) row_ptr[N] = E;
    if (i < N){
        int d  = deg[i];
        int rp = row_ptr[i] - d + bsum[blockIdx.x];
        row_ptr[i] = rp;
        cursor[i]  = rp;
        inv_deg[i] = 1.0f / (float)(d > 1 ? d : 1);
    }
}

__global__ void k_fill(const int* __restrict__ src, const int* __restrict__ dst,
                       int E, int* __restrict__ cursor, int* __restrict__ col_idx){
    int i = blockIdx.x*blockDim.x + threadIdx.x;
    if (i < E){
        int p = atomicAdd(&cursor[dst[i]], 1);
        col_idx[p] = src[i];
    }
}

// ---------------------------------------------------------------- conversions
__global__ void k_cvt_x(const float* __restrict__ in, ushort* __restrict__ out, int n4){
    int i = blockIdx.x*blockDim.x + threadIdx.x;
    if (i >= n4) return;
    float4 v = reinterpret_cast<const float4*>(in)[i];
    ushort4 o; o.x=f2b(v.x); o.y=f2b(v.y); o.z=f2b(v.z); o.w=f2b(v.w);
    reinterpret_cast<ushort4*>(out)[i] = o;
}

// in: [nslab][K][C] f32 -> out: [nslab][C][K] bf16 (transposed per slab)
__global__ void k_cvt_t(const float* __restrict__ in, ushort* __restrict__ out,
                        int K, int C, int total){
    int i = blockIdx.x*blockDim.x + threadIdx.x;
    if (i >= total) return;
    int kc = K*C;
    int s = i / kc, r = i - s*kc;
    int k = r / C, c = r - k*C;
    out[s*kc + c*K + k] = f2b(in[i]);
}

// ---------------------------------------------------------------- aggregation (bf16)
// one wave per node; 4 lane-groups of 16, each gathers a different edge with
// dwordx4 (16 lanes x 16B = full 256B row); 2-deep manual pipeline => 8
// outstanding gathers/wave. Cross-group reduce via shfl_xor(16,32).
__global__ __launch_bounds__(256) void k_agg_bf(
    const ushort* __restrict__ h, const int* __restrict__ row_ptr,
    const int* __restrict__ col_idx, const float* __restrict__ inv_deg,
    ushort* __restrict__ agg, int N)
{
    int node = (blockIdx.x*blockDim.x + threadIdx.x) >> 6;
    int lane = threadIdx.x & 63;
    if (node >= N) return;
    const int g = lane >> 4, l15 = lane & 15;
    const int beg = row_ptr[node], end = row_ptr[node+1];

    float a[8];
    #pragma unroll
    for (int q = 0; q < 8; ++q) a[q] = 0.f;

    int j = beg + g;
    while (j + 4 < end){
        int s0 = col_idx[j];
        int s1 = col_idx[j+4];
        uint4 v0 = *reinterpret_cast<const uint4*>(h + (size_t)s0*128 + l15*8);
        uint4 v1 = *reinterpret_cast<const uint4*>(h + (size_t)s1*128 + l15*8);
        uint w0[4] = {v0.x, v0.y, v0.z, v0.w};
        uint w1[4] = {v1.x, v1.y, v1.z, v1.w};
        #pragma unroll
        for (int q = 0; q < 4; ++q){
            a[2*q]   += b2f((ushort)(w0[q] & 0xffffu)) + b2f((ushort)(w1[q] & 0xffffu));
            a[2*q+1] += b2f((ushort)(w0[q] >> 16))     + b2f((ushort)(w1[q] >> 16));
        }
        j += 8;
    }
    if (j < end){
        int s0 = col_idx[j];
        uint4 v0 = *reinterpret_cast<const uint4*>(h + (size_t)s0*128 + l15*8);
        uint w0[4] = {v0.x, v0.y, v0.z, v0.w};
        #pragma unroll
        for (int q = 0; q < 4; ++q){
            a[2*q]   += b2f((ushort)(w0[q] & 0xffffu));
            a[2*q+1] += b2f((ushort)(w0[q] >> 16));
        }
    }

    #pragma unroll
    for (int q = 0; q < 8; ++q){
        a[q] += __shfl_xor(a[q], 16);
        a[q] += __shfl_xor(a[q], 32);
    }

    if (g == 0){
        float sc = inv_deg[node];
        uint r[4];
        #pragma unroll
        for (int q = 0; q < 4; ++q)
            r[q] = (uint)f2b(a[2*q]*sc) | ((uint)f2b(a[2*q+1]*sc) << 16);
        *reinterpret_cast<uint4*>(agg + (size_t)node*128 + l15*8) =
            make_uint4(r[0], r[1], r[2], r[3]);
    }
}

// ---------------------------------------------------------------- MFMA GEMM
// out[N, NCF*16] = sum_p A_p[N,128](bf16) @ T_p[NCF*16][128]^T(bf16) + bias
template<int NCF, int STATS, int OUTBF>
__global__ __launch_bounds__(256) void k_gemm_mfma(
    const ushort* __restrict__ A0, const ushort* __restrict__ T0,
    const ushort* __restrict__ A1, const ushort* __restrict__ T1,
    const ushort* __restrict__ A2, const ushort* __restrict__ T2,
    const ushort* __restrict__ A3, const ushort* __restrict__ T3,
    int P, const float* __restrict__ bias,
    ushort* __restrict__ out_bf, float* __restrict__ out_f32,
    float* __restrict__ partials, int N)
{
    __shared__ ushort Ws[NCF*16*128];
    const int t   = threadIdx.x;
    const int w   = t >> 6, l = t & 63;
    const int l15 = l & 15, lg = l >> 4;
    const int r0   = blockIdx.x * 128;
    const int wrow = w * 32;

    f32x4 acc[2][NCF];
    #pragma unroll
    for (int i = 0; i < 2; ++i)
        #pragma unroll
        for (int j = 0; j < NCF; ++j) acc[i][j] = (f32x4){0.f,0.f,0.f,0.f};

    for (int p = 0; p < P; ++p){
        const ushort* A = (p==0)?A0:(p==1)?A1:(p==2)?A2:A3;
        const ushort* T = (p==0)?T0:(p==1)?T1:(p==2)?T2:T3;
        if (p) __syncthreads();
        #pragma unroll
        for (int q = 0; q < NCF; ++q){
            int lin  = q*256 + t;
            int row  = lin >> 4, c16 = lin & 15;
            int c16s = c16 ^ (row & 7);
            uint4 v = *reinterpret_cast<const uint4*>(T + (size_t)row*128 + c16*8);
            *reinterpret_cast<uint4*>(&Ws[row*128 + c16s*8]) = v;
        }
        __syncthreads();
        #pragma unroll
        for (int kk = 0; kk < 4; ++kk){
            const int k0 = kk*32;
            short8_t a[2];
            #pragma unroll
            for (int rf = 0; rf < 2; ++rf){
                size_t gr = (size_t)(r0 + wrow + rf*16 + l15);
                a[rf] = *reinterpret_cast<const short8_t*>(A + gr*128 + k0 + lg*8);
            }
            #pragma unroll
            for (int cf = 0; cf < NCF; ++cf){
                int row  = cf*16 + l15;
                int c16  = (k0 >> 3) + lg;
                int c16s = c16 ^ (row & 7);
                short8_t b = *reinterpret_cast<const short8_t*>(&Ws[row*128 + c16s*8]);
                acc[0][cf] = __builtin_amdgcn_mfma_f32_16x16x32_bf16(a[0], b, acc[0][cf], 0, 0, 0);
                acc[1][cf] = __builtin_amdgcn_mfma_f32_16x16x32_bf16(a[1], b, acc[1][cf], 0, 0, 0);
            }
        }
    }

    float bs[NCF];
    #pragma unroll
    for (int cf = 0; cf < NCF; ++cf) bs[cf] = bias[cf*16 + l15];

    float s1[NCF], s2[NCF];
    #pragma unroll
    for (int cf = 0; cf < NCF; ++cf){ s1[cf] = 0.f; s2[cf] = 0.f; }

    #pragma unroll
    for (int rf = 0; rf < 2; ++rf){
        #pragma unroll
        for (int q = 0; q < 4; ++q){
            int gr = r0 + wrow + rf*16 + lg*4 + q;
            bool valid = gr < N;
            #pragma unroll
            for (int cf = 0; cf < NCF; ++cf){
                float v = acc[rf][cf][q] + bs[cf];
                if (valid){
                    if (STATS){ s1[cf] += v; s2[cf] += v*v; }
                    int col = cf*16 + l15;
                    if (OUTBF) out_bf[(size_t)gr*(NCF*16) + col] = f2b(v);
                    else       out_f32[(size_t)gr*(NCF*16) + col] = v;
                }
            }
        }
    }
    if (STATS){
        #pragma unroll
        for (int cf = 0; cf < NCF; ++cf){
            s1[cf] += __shfl_xor(s1[cf], 16);
            s1[cf] += __shfl_xor(s1[cf], 32);
            s2[cf] += __shfl_xor(s2[cf], 16);
            s2[cf] += __shfl_xor(s2[cf], 32);
        }
        if (l < 16){
            float* pb = partials + (size_t)(blockIdx.x*4 + w)*256;
            #pragma unroll
            for (int cf = 0; cf < NCF; ++cf){
                pb[cf*16 + l15]       = s1[cf];
                pb[128 + cf*16 + l15] = s2[cf];
            }
        }
    }
}

// ---------------------------------------------------------------- BN reduce
__global__ void k_bnreduce(const float* __restrict__ partials, int I, int N,
                           const float* __restrict__ gamma, const float* __restrict__ beta,
                           float* __restrict__ ss)
{
    int c = blockIdx.x;
    int l = threadIdx.x;
    float s1 = 0.f, s2 = 0.f;
    for (int i = l; i < I; i += 64){
        s1 += partials[(size_t)i*256 + c];
        s2 += partials[(size_t)i*256 + 128 + c];
    }
    #pragma unroll
    for (int off = 32; off; off >>= 1){
        s1 += __shfl_xor(s1, off);
        s2 += __shfl_xor(s2, off);
    }
    if (l == 0){
        float m   = s1 / (float)N;
        float var = s2 / (float)N - m*m;
        float sc  = rsqrtf(var + 1e-5f) * gamma[c];
        ss[c]     = sc;
        ss[128+c] = beta[c] - m*sc;
    }
}

// ---------------------------------------------------------------- norm + act (bf16)
template<int LEAKY>
__global__ __launch_bounds__(256) void k_norm_act_bf(
    const ushort* __restrict__ pre, const float* __restrict__ ss,
    ushort* __restrict__ out, int total8)
{
    int i = blockIdx.x*blockDim.x + threadIdx.x;
    if (i >= total8) return;
    uint4 v = reinterpret_cast<const uint4*>(pre)[i];
    int c0 = (i & 15) * 8;
    uint vv[4] = {v.x, v.y, v.z, v.w};
    uint r[4];
    #pragma unroll
    for (int q = 0; q < 4; ++q){
        float f0 = b2f((ushort)(vv[q] & 0xffffu)) * ss[c0+q*2]   + ss[128+c0+q*2];
        float f1 = b2f((ushort)(vv[q] >> 16))     * ss[c0+q*2+1] + ss[128+c0+q*2+1];
        if (LEAKY){ f0 = f0 > 0.f ? f0 : 0.01f*f0; f1 = f1 > 0.f ? f1 : 0.01f*f1; }
        else      { f0 = fmaxf(f0, 0.f); f1 = fmaxf(f1, 0.f); }
        r[q] = (uint)f2b(f0) | ((uint)f2b(f1) << 16);
    }
    reinterpret_cast<uint4*>(out)[i] = make_uint4(r[0], r[1], r[2], r[3]);
}

// ---------------------------------------------------------------- launch
extern "C" void kernel_launch(void* const* d_in, const int* in_sizes, int n_in,
                              void* d_out, int out_size, void* d_ws, size_t ws_size,
                              hipStream_t stream)
{
    const float* x     = (const float*)d_in[0];
    const int*   ei    = (const int*)  d_in[1];
    const float* Wl    = (const float*)d_in[2];
    const float* bl    = (const float*)d_in[3];
    const float* Wr    = (const float*)d_in[4];
    const float* gamma = (const float*)d_in[5];
    const float* beta  = (const float*)d_in[6];
    const float* W1    = (const float*)d_in[7];
    const float* b1    = (const float*)d_in[8];
    const float* g1    = (const float*)d_in[9];
    const float* be1   = (const float*)d_in[10];
    const float* W2    = (const float*)d_in[11];
    const float* b2    = (const float*)d_in[12];
    float* out = (float*)d_out;

    const int N  = in_sizes[0] / 128;
    const int E  = in_sizes[1] / 2;
    const int NB = CDIV(N, 128);
    const size_t NPAD = (size_t)NB * 128;
    const int* src = ei;
    const int* dst = ei + E;

    char* w = (char*)d_ws;
    const size_t SB = NPAD * 128 * sizeof(ushort);
    ushort* x_bf = (ushort*)(w + 0*SB);
    ushort* h0   = (ushort*)(w + 1*SB);
    ushort* h1   = (ushort*)(w + 2*SB);
    ushort* h2   = (ushort*)(w + 3*SB);
    ushort* aggb = (ushort*)(w + 4*SB);
    ushort* preb = (ushort*)(w + 5*SB);
    char* p = w + 6*SB;
    ushort* WtL = (ushort*)p;  p += (size_t)3*16384*2;
    ushort* WtR = (ushort*)p;  p += (size_t)3*16384*2;
    ushort* Wt1 = (ushort*)p;  p += (size_t)4*16384*2;
    ushort* Wt2 = (ushort*)p;  p += (size_t)8192*2;
    float* partials = (float*)p; p += (size_t)NB*4*256*sizeof(float);
    int*   col_idx  = (int*)p;   p += (size_t)E*4;
    int*   row_ptr  = (int*)p;   p += (size_t)(N+1)*4;
    int*   cursor   = (int*)p;   p += (size_t)N*4;
    int*   deg      = (int*)p;   p += (size_t)N*4;
    float* inv_deg  = (float*)p; p += (size_t)N*4;
    int*   bsum     = (int*)p;   p += 1024*4;
    float* ssb      = (float*)p; p += 256*4;

    const int SCAN_B = CDIV(N, 1024);

    const int n4 = N * 32;
    k_cvt_x<<<CDIV(n4,256), 256, 0, stream>>>(x, x_bf, n4);
    k_cvt_t<<<CDIV(3*16384,256), 256, 0, stream>>>(Wl, WtL, 128, 128, 3*16384);
    k_cvt_t<<<CDIV(3*16384,256), 256, 0, stream>>>(Wr, WtR, 128, 128, 3*16384);
    k_cvt_t<<<CDIV(4*16384,256), 256, 0, stream>>>(W1, Wt1, 128, 128, 4*16384);
    k_cvt_t<<<CDIV(8192,256),    256, 0, stream>>>(W2, Wt2, 128,  64, 8192);

    hipMemsetAsync(deg, 0, (size_t)N*4, stream);
    k_deg<<<CDIV(E,256), 256, 0, stream>>>(dst, E, deg);
    k_scan1<<<SCAN_B, 1024, 0, stream>>>(deg, N, row_ptr, bsum);
    k_scan2<<<1, 1024, 0, stream>>>(bsum, SCAN_B);
    k_scan3<<<SCAN_B, 1024, 0, stream>>>(deg, bsum, N, E, row_ptr, cursor, inv_deg);
    k_fill<<<CDIV(E,256), 256, 0, stream>>>(src, dst, E, cursor, col_idx);

    const ushort* h = x_bf;
    ushort* hb[3] = {h0, h1, h2};
    const int total8 = N * 16;
    for (int L = 0; L < 3; ++L){
        k_agg_bf<<<CDIV(N,4), 256, 0, stream>>>(h, row_ptr, col_idx, inv_deg, aggb, N);
        k_gemm_mfma<8,1,1><<<NB, 256, 0, stream>>>(
            aggb, WtL + (size_t)L*16384,
            h,    WtR + (size_t)L*16384,
            nullptr, nullptr, nullptr, nullptr,
            2, bl + (size_t)L*128, preb, nullptr, partials, N);
        k_bnreduce<<<128, 64, 0, stream>>>(partials, NB*4, N,
            gamma + (size_t)L*128, beta + (size_t)L*128, ssb);
        k_norm_act_bf<0><<<CDIV(total8,256), 256, 0, stream>>>(preb, ssb, hb[L], total8);
        h = hb[L];
    }

    k_gemm_mfma<8,1,1><<<NB, 256, 0, stream>>>(
        x_bf, Wt1 + 0,
        h0,   Wt1 + 16384,
        h1,   Wt1 + 2*16384,
        h2,   Wt1 + 3*16384,
        4, b1, preb, nullptr, partials, N);
    k_bnreduce<<<128, 64, 0, stream>>>(partials, NB*4, N, g1, be1, ssb);
    k_norm_act_bf<1><<<CDIV(total8,256), 256, 0, stream>>>(preb, ssb, aggb, total8);

    k_gemm_mfma<4,0,0><<<NB, 256, 0, stream>>>(
        aggb, Wt2, nullptr, nullptr, nullptr, nullptr, nullptr, nullptr,
        1, b2, nullptr, out, nullptr, N);
}

// Round 4
// 598.993 us; speedup vs baseline: 2.6960x; 1.1045x over previous
//
#include <hip/hip_runtime.h>
#include <hip/hip_bf16.h>

#define CDIV(a,b) (((a)+(b)-1)/(b))

typedef __attribute__((ext_vector_type(8))) short short8_t;
typedef __attribute__((ext_vector_type(4))) float f32x4;

__device__ __forceinline__ float b2f(ushort u){
    union { uint i; float f; } v; v.i = ((uint)u) << 16; return v.f;
}
__device__ __forceinline__ ushort f2b(float f){
    __hip_bfloat16 h = __float2bfloat16(f);
    return *reinterpret_cast<ushort*>(&h);
}

// ---------------------------------------------------------------- CSR build
__global__ void k_deg(const int* __restrict__ dst, int E, int* __restrict__ deg){
    int i = blockIdx.x*blockDim.x + threadIdx.x;
    if (i < E) atomicAdd(&deg[dst[i]], 1);
}

__global__ void k_scan1(const int* __restrict__ deg, int N,
                        int* __restrict__ row_ptr, int* __restrict__ bsum){
    __shared__ int s[1024];
    int t = threadIdx.x;
    int i = blockIdx.x*1024 + t;
    int v = (i < N) ? deg[i] : 0;
    s[t] = v;
    __syncthreads();
    for (int off = 1; off < 1024; off <<= 1){
        int x = (t >= off) ? s[t-off] : 0;
        __syncthreads();
        s[t] += x;
        __syncthreads();
    }
    if (i < N) row_ptr[i] = s[t];
    if (t == 1023) bsum[blockIdx.x] = s[1023];
}

__global__ void k_scan2(int* __restrict__ bsum, int B){
    __shared__ int s[1024];
    int t = threadIdx.x;
    int v = (t < B) ? bsum[t] : 0;
    s[t] = v;
    __syncthreads();
    for (int off = 1; off < 1024; off <<= 1){
        int x = (t >= off) ? s[t-off] : 0;
        __syncthreads();
        s[t] += x;
        __syncthreads();
    }
    if (t < B) bsum[t] = s[t] - v;  // exclusive
}

__global__ void k_scan3(const int* __restrict__ deg, const int* __restrict__ bsum,
                        int N, int E, int* __restrict__ row_ptr,
                        int* __restrict__ cursor, float* __restrict__ inv_deg){
    int i = blockIdx.x*1024 + threadIdx.x;
    if (i == 0) row_ptr[N] = E;
    if (i < N){
        int d  = deg[i];
        int rp = row_ptr[i] - d + bsum[blockIdx.x];
        row_ptr[i] = rp;
        cursor[i]  = rp;
        inv_deg[i] = 1.0f / (float)(d > 1 ? d : 1);
    }
}

// gcur[b] = start of bucket b's region in CSR layout
__global__ void k_binit(const int* __restrict__ row_ptr, int shift, int nbuck,
                        int* __restrict__ gcur){
    int i = blockIdx.x*blockDim.x + threadIdx.x;
    if (i < nbuck) gcur[i] = row_ptr[i << shift];
}

// pass A: scatter (src,dst) pairs into dst-bucket regions (CSR-region layout)
__global__ __launch_bounds__(256) void k_bucketA(
    const int* __restrict__ src, const int* __restrict__ dst, int E,
    int shift, int nbuck, int* __restrict__ gcur, uint2* __restrict__ ebuf)
{
    __shared__ int cnt[512];
    __shared__ int base[512];
    const int t  = threadIdx.x;
    const int e0 = blockIdx.x * 4096;
    for (int i = t; i < nbuck; i += 256) cnt[i] = 0;
    __syncthreads();
    int ms[16], md[16];
    #pragma unroll
    for (int q = 0; q < 16; ++q){
        int idx = e0 + q*256 + t;
        int d = -1, s = 0;
        if (idx < E){ s = src[idx]; d = dst[idx]; atomicAdd(&cnt[d >> shift], 1); }
        ms[q] = s; md[q] = d;
    }
    __syncthreads();
    for (int i = t; i < nbuck; i += 256){
        int c = cnt[i];
        base[i] = c ? atomicAdd(&gcur[i], c) : 0;
    }
    __syncthreads();
    for (int i = t; i < nbuck; i += 256) cnt[i] = 0;
    __syncthreads();
    #pragma unroll
    for (int q = 0; q < 16; ++q){
        if (md[q] >= 0){
            int b   = md[q] >> shift;
            int pos = base[b] + atomicAdd(&cnt[b], 1);
            ebuf[pos] = make_uint2((uint)ms[q], (uint)md[q]);
        }
    }
}

// pass B: per-bucket cursor fill; atomics+writes stay in one CU's L2 range
__global__ __launch_bounds__(256) void k_fillB(
    const uint2* __restrict__ ebuf, const int* __restrict__ row_ptr,
    int shift, int N, int* __restrict__ cursor, int* __restrict__ col_idx)
{
    int b  = blockIdx.x;
    int n0 = b << shift;
    int n1 = min((b+1) << shift, N);
    int lo = row_ptr[n0], hi = row_ptr[n1];
    for (int j = lo + (int)threadIdx.x; j < hi; j += 256){
        uint2 e = ebuf[j];
        int p = atomicAdd(&cursor[(int)e.y], 1);
        col_idx[p] = (int)e.x;
    }
}

// ---------------------------------------------------------------- conversions
__global__ void k_cvt_x(const float* __restrict__ in, ushort* __restrict__ out, int n4){
    int i = blockIdx.x*blockDim.x + threadIdx.x;
    if (i >= n4) return;
    float4 v = reinterpret_cast<const float4*>(in)[i];
    ushort4 o; o.x=f2b(v.x); o.y=f2b(v.y); o.z=f2b(v.z); o.w=f2b(v.w);
    reinterpret_cast<ushort4*>(out)[i] = o;
}

// in: [nslab][K][C] f32 -> out: [nslab][C][K] bf16 (transposed per slab)
__global__ void k_cvt_t(const float* __restrict__ in, ushort* __restrict__ out,
                        int K, int C, int total){
    int i = blockIdx.x*blockDim.x + threadIdx.x;
    if (i >= total) return;
    int kc = K*C;
    int s = i / kc, r = i - s*kc;
    int k = r / C, c = r - k*C;
    out[s*kc + c*K + k] = f2b(in[i]);
}

// ---------------------------------------------------------------- aggregation (bf16)
__global__ __launch_bounds__(256) void k_agg_bf(
    const ushort* __restrict__ h, const int* __restrict__ row_ptr,
    const int* __restrict__ col_idx, const float* __restrict__ inv_deg,
    ushort* __restrict__ agg, int N)
{
    int node = (blockIdx.x*blockDim.x + threadIdx.x) >> 6;
    int lane = threadIdx.x & 63;
    if (node >= N) return;
    const int g = lane >> 4, l15 = lane & 15;
    const int beg = row_ptr[node], end = row_ptr[node+1];

    float a[8];
    #pragma unroll
    for (int q = 0; q < 8; ++q) a[q] = 0.f;

    int j = beg + g;
    while (j + 4 < end){
        int s0 = col_idx[j];
        int s1 = col_idx[j+4];
        uint4 v0 = *reinterpret_cast<const uint4*>(h + (size_t)s0*128 + l15*8);
        uint4 v1 = *reinterpret_cast<const uint4*>(h + (size_t)s1*128 + l15*8);
        uint w0[4] = {v0.x, v0.y, v0.z, v0.w};
        uint w1[4] = {v1.x, v1.y, v1.z, v1.w};
        #pragma unroll
        for (int q = 0; q < 4; ++q){
            a[2*q]   += b2f((ushort)(w0[q] & 0xffffu)) + b2f((ushort)(w1[q] & 0xffffu));
            a[2*q+1] += b2f((ushort)(w0[q] >> 16))     + b2f((ushort)(w1[q] >> 16));
        }
        j += 8;
    }
    if (j < end){
        int s0 = col_idx[j];
        uint4 v0 = *reinterpret_cast<const uint4*>(h + (size_t)s0*128 + l15*8);
        uint w0[4] = {v0.x, v0.y, v0.z, v0.w};
        #pragma unroll
        for (int q = 0; q < 4; ++q){
            a[2*q]   += b2f((ushort)(w0[q] & 0xffffu));
            a[2*q+1] += b2f((ushort)(w0[q] >> 16));
        }
    }

    #pragma unroll
    for (int q = 0; q < 8; ++q){
        a[q] += __shfl_xor(a[q], 16);
        a[q] += __shfl_xor(a[q], 32);
    }

    if (g == 0){
        float sc = inv_deg[node];
        uint r[4];
        #pragma unroll
        for (int q = 0; q < 4; ++q)
            r[q] = (uint)f2b(a[2*q]*sc) | ((uint)f2b(a[2*q+1]*sc) << 16);
        *reinterpret_cast<uint4*>(agg + (size_t)node*128 + l15*8) =
            make_uint4(r[0], r[1], r[2], r[3]);
    }
}

// ---------------------------------------------------------------- MFMA GEMM
template<int NCF, int STATS, int OUTBF>
__global__ __launch_bounds__(256) void k_gemm_mfma(
    const ushort* __restrict__ A0, const ushort* __restrict__ T0,
    const ushort* __restrict__ A1, const ushort* __restrict__ T1,
    const ushort* __restrict__ A2, const ushort* __restrict__ T2,
    const ushort* __restrict__ A3, const ushort* __restrict__ T3,
    int P, const float* __restrict__ bias,
    ushort* __restrict__ out_bf, float* __restrict__ out_f32,
    float* __restrict__ partials, int N)
{
    __shared__ ushort Ws[NCF*16*128];
    const int t   = threadIdx.x;
    const int w   = t >> 6, l = t & 63;
    const int l15 = l & 15, lg = l >> 4;
    const int r0   = blockIdx.x * 128;
    const int wrow = w * 32;

    f32x4 acc[2][NCF];
    #pragma unroll
    for (int i = 0; i < 2; ++i)
        #pragma unroll
        for (int j = 0; j < NCF; ++j) acc[i][j] = (f32x4){0.f,0.f,0.f,0.f};

    for (int p = 0; p < P; ++p){
        const ushort* A = (p==0)?A0:(p==1)?A1:(p==2)?A2:A3;
        const ushort* T = (p==0)?T0:(p==1)?T1:(p==2)?T2:T3;
        if (p) __syncthreads();
        #pragma unroll
        for (int q = 0; q < NCF; ++q){
            int lin  = q*256 + t;
            int row  = lin >> 4, c16 = lin & 15;
            int c16s = c16 ^ (row & 7);
            uint4 v = *reinterpret_cast<const uint4*>(T + (size_t)row*128 + c16*8);
            *reinterpret_cast<uint4*>(&Ws[row*128 + c16s*8]) = v;
        }
        __syncthreads();
        #pragma unroll
        for (int kk = 0; kk < 4; ++kk){
            const int k0 = kk*32;
            short8_t a[2];
            #pragma unroll
            for (int rf = 0; rf < 2; ++rf){
                size_t gr = (size_t)(r0 + wrow + rf*16 + l15);
                a[rf] = *reinterpret_cast<const short8_t*>(A + gr*128 + k0 + lg*8);
            }
            #pragma unroll
            for (int cf = 0; cf < NCF; ++cf){
                int row  = cf*16 + l15;
                int c16  = (k0 >> 3) + lg;
                int c16s = c16 ^ (row & 7);
                short8_t b = *reinterpret_cast<const short8_t*>(&Ws[row*128 + c16s*8]);
                acc[0][cf] = __builtin_amdgcn_mfma_f32_16x16x32_bf16(a[0], b, acc[0][cf], 0, 0, 0);
                acc[1][cf] = __builtin_amdgcn_mfma_f32_16x16x32_bf16(a[1], b, acc[1][cf], 0, 0, 0);
            }
        }
    }

    float bs[NCF];
    #pragma unroll
    for (int cf = 0; cf < NCF; ++cf) bs[cf] = bias[cf*16 + l15];

    float s1[NCF], s2[NCF];
    #pragma unroll
    for (int cf = 0; cf < NCF; ++cf){ s1[cf] = 0.f; s2[cf] = 0.f; }

    #pragma unroll
    for (int rf = 0; rf < 2; ++rf){
        #pragma unroll
        for (int q = 0; q < 4; ++q){
            int gr = r0 + wrow + rf*16 + lg*4 + q;
            bool valid = gr < N;
            #pragma unroll
            for (int cf = 0; cf < NCF; ++cf){
                float v = acc[rf][cf][q] + bs[cf];
                if (valid){
                    if (STATS){ s1[cf] += v; s2[cf] += v*v; }
                    int col = cf*16 + l15;
                    if (OUTBF) out_bf[(size_t)gr*(NCF*16) + col] = f2b(v);
                    else       out_f32[(size_t)gr*(NCF*16) + col] = v;
                }
            }
        }
    }
    if (STATS){
        #pragma unroll
        for (int cf = 0; cf < NCF; ++cf){
            s1[cf] += __shfl_xor(s1[cf], 16);
            s1[cf] += __shfl_xor(s1[cf], 32);
            s2[cf] += __shfl_xor(s2[cf], 16);
            s2[cf] += __shfl_xor(s2[cf], 32);
        }
        if (l < 16){
            float* pb = partials + (size_t)(blockIdx.x*4 + w)*256;
            #pragma unroll
            for (int cf = 0; cf < NCF; ++cf){
                pb[cf*16 + l15]       = s1[cf];
                pb[128 + cf*16 + l15] = s2[cf];
            }
        }
    }
}

// ---------------------------------------------------------------- BN reduce
__global__ void k_bnreduce(const float* __restrict__ partials, int I, int N,
                           const float* __restrict__ gamma, const float* __restrict__ beta,
                           float* __restrict__ ss)
{
    int c = blockIdx.x;
    int l = threadIdx.x;
    float s1 = 0.f, s2 = 0.f;
    for (int i = l; i < I; i += 64){
        s1 += partials[(size_t)i*256 + c];
        s2 += partials[(size_t)i*256 + 128 + c];
    }
    #pragma unroll
    for (int off = 32; off; off >>= 1){
        s1 += __shfl_xor(s1, off);
        s2 += __shfl_xor(s2, off);
    }
    if (l == 0){
        float m   = s1 / (float)N;
        float var = s2 / (float)N - m*m;
        float sc  = rsqrtf(var + 1e-5f) * gamma[c];
        ss[c]     = sc;
        ss[128+c] = beta[c] - m*sc;
    }
}

// ---------------------------------------------------------------- norm + act (bf16)
template<int LEAKY>
__global__ __launch_bounds__(256) void k_norm_act_bf(
    const ushort* __restrict__ pre, const float* __restrict__ ss,
    ushort* __restrict__ out, int total8)
{
    int i = blockIdx.x*blockDim.x + threadIdx.x;
    if (i >= total8) return;
    uint4 v = reinterpret_cast<const uint4*>(pre)[i];
    int c0 = (i & 15) * 8;
    uint vv[4] = {v.x, v.y, v.z, v.w};
    uint r[4];
    #pragma unroll
    for (int q = 0; q < 4; ++q){
        float f0 = b2f((ushort)(vv[q] & 0xffffu)) * ss[c0+q*2]   + ss[128+c0+q*2];
        float f1 = b2f((ushort)(vv[q] >> 16))     * ss[c0+q*2+1] + ss[128+c0+q*2+1];
        if (LEAKY){ f0 = f0 > 0.f ? f0 : 0.01f*f0; f1 = f1 > 0.f ? f1 : 0.01f*f1; }
        else      { f0 = fmaxf(f0, 0.f); f1 = fmaxf(f1, 0.f); }
        r[q] = (uint)f2b(f0) | ((uint)f2b(f1) << 16);
    }
    reinterpret_cast<uint4*>(out)[i] = make_uint4(r[0], r[1], r[2], r[3]);
}

// ---------------------------------------------------------------- launch
extern "C" void kernel_launch(void* const* d_in, const int* in_sizes, int n_in,
                              void* d_out, int out_size, void* d_ws, size_t ws_size,
                              hipStream_t stream)
{
    const float* x     = (const float*)d_in[0];
    const int*   ei    = (const int*)  d_in[1];
    const float* Wl    = (const float*)d_in[2];
    const float* bl    = (const float*)d_in[3];
    const float* Wr    = (const float*)d_in[4];
    const float* gamma = (const float*)d_in[5];
    const float* beta  = (const float*)d_in[6];
    const float* W1    = (const float*)d_in[7];
    const float* b1    = (const float*)d_in[8];
    const float* g1    = (const float*)d_in[9];
    const float* be1   = (const float*)d_in[10];
    const float* W2    = (const float*)d_in[11];
    const float* b2    = (const float*)d_in[12];
    float* out = (float*)d_out;

    const int N  = in_sizes[0] / 128;
    const int E  = in_sizes[1] / 2;
    const int NB = CDIV(N, 128);
    const size_t NPAD = (size_t)NB * 128;
    const int* src = ei;
    const int* dst = ei + E;

    int shift = 8;
    while (CDIV(N, 1 << shift) > 512) ++shift;
    const int NBUCK = CDIV(N, 1 << shift);

    char* w = (char*)d_ws;
    const size_t SB = NPAD * 128 * sizeof(ushort);
    ushort* x_bf = (ushort*)(w + 0*SB);
    ushort* h0   = (ushort*)(w + 1*SB);
    ushort* h1   = (ushort*)(w + 2*SB);
    ushort* h2   = (ushort*)(w + 3*SB);
    ushort* aggb = (ushort*)(w + 4*SB);
    ushort* preb = (ushort*)(w + 5*SB);
    char* p = w + 6*SB;
    ushort* WtL = (ushort*)p;  p += (size_t)3*16384*2;
    ushort* WtR = (ushort*)p;  p += (size_t)3*16384*2;
    ushort* Wt1 = (ushort*)p;  p += (size_t)4*16384*2;
    ushort* Wt2 = (ushort*)p;  p += (size_t)8192*2;
    float* partials = (float*)p; p += (size_t)NB*4*256*sizeof(float);
    uint2* ebuf     = (uint2*)p; p += (size_t)E*8;
    int*   col_idx  = (int*)p;   p += (size_t)E*4;
    int*   row_ptr  = (int*)p;   p += (size_t)(N+1)*4;
    int*   cursor   = (int*)p;   p += (size_t)N*4;
    int*   deg      = (int*)p;   p += (size_t)N*4;
    float* inv_deg  = (float*)p; p += (size_t)N*4;
    int*   bsum     = (int*)p;   p += 1024*4;
    int*   gcur     = (int*)p;   p += 512*4;
    float* ssb      = (float*)p; p += 256*4;

    const int SCAN_B = CDIV(N, 1024);

    const int n4 = N * 32;
    k_cvt_x<<<CDIV(n4,256), 256, 0, stream>>>(x, x_bf, n4);
    k_cvt_t<<<CDIV(3*16384,256), 256, 0, stream>>>(Wl, WtL, 128, 128, 3*16384);
    k_cvt_t<<<CDIV(3*16384,256), 256, 0, stream>>>(Wr, WtR, 128, 128, 3*16384);
    k_cvt_t<<<CDIV(4*16384,256), 256, 0, stream>>>(W1, Wt1, 128, 128, 4*16384);
    k_cvt_t<<<CDIV(8192,256),    256, 0, stream>>>(W2, Wt2, 128,  64, 8192);

    hipMemsetAsync(deg, 0, (size_t)N*4, stream);
    k_deg<<<CDIV(E,256), 256, 0, stream>>>(dst, E, deg);
    k_scan1<<<SCAN_B, 1024, 0, stream>>>(deg, N, row_ptr, bsum);
    k_scan2<<<1, 1024, 0, stream>>>(bsum, SCAN_B);
    k_scan3<<<SCAN_B, 1024, 0, stream>>>(deg, bsum, N, E, row_ptr, cursor, inv_deg);
    k_binit<<<CDIV(NBUCK,256), 256, 0, stream>>>(row_ptr, shift, NBUCK, gcur);
    k_bucketA<<<CDIV(E,4096), 256, 0, stream>>>(src, dst, E, shift, NBUCK, gcur, ebuf);
    k_fillB<<<NBUCK, 256, 0, stream>>>(ebuf, row_ptr, shift, N, cursor, col_idx);

    const ushort* h = x_bf;
    ushort* hb[3] = {h0, h1, h2};
    const int total8 = N * 16;
    for (int L = 0; L < 3; ++L){
        k_agg_bf<<<CDIV(N,4), 256, 0, stream>>>(h, row_ptr, col_idx, inv_deg, aggb, N);
        k_gemm_mfma<8,1,1><<<NB, 256, 0, stream>>>(
            aggb, WtL + (size_t)L*16384,
            h,    WtR + (size_t)L*16384,
            nullptr, nullptr, nullptr, nullptr,
            2, bl + (size_t)L*128, preb, nullptr, partials, N);
        k_bnreduce<<<128, 64, 0, stream>>>(partials, NB*4, N,
            gamma + (size_t)L*128, beta + (size_t)L*128, ssb);
        k_norm_act_bf<0><<<CDIV(total8,256), 256, 0, stream>>>(preb, ssb, hb[L], total8);
        h = hb[L];
    }

    k_gemm_mfma<8,1,1><<<NB, 256, 0, stream>>>(
        x_bf, Wt1 + 0,
        h0,   Wt1 + 16384,
        h1,   Wt1 + 2*16384,
        h2,   Wt1 + 3*16384,
        4, b1, preb, nullptr, partials, N);
    k_bnreduce<<<128, 64, 0, stream>>>(partials, NB*4, N, g1, be1, ssb);
    k_norm_act_bf<1><<<CDIV(total8,256), 256, 0, stream>>>(preb, ssb, aggb, total8);

    k_gemm_mfma<4,0,0><<<NB, 256, 0, stream>>>(
        aggb, Wt2, nullptr, nullptr, nullptr, nullptr, nullptr, nullptr,
        1, b2, nullptr, out, nullptr, N);
}

// Round 5
// 521.243 us; speedup vs baseline: 3.0981x; 1.1492x over previous
//
#include <hip/hip_runtime.h>
#include <hip/hip_bf16.h>

#define CDIV(a,b) (((a)+(b)-1)/(b))

typedef __attribute__((ext_vector_type(8))) short short8_t;
typedef __attribute__((ext_vector_type(4))) float f32x4;

__device__ __forceinline__ float b2f(ushort u){
    union { uint i; float f; } v; v.i = ((uint)u) << 16; return v.f;
}
__device__ __forceinline__ ushort f2b(float f){
    __hip_bfloat16 h = __float2bfloat16(f);
    return *reinterpret_cast<ushort*>(&h);
}

// ---------------------------------------------------------------- bucketed CSR build
// buckets of 256 nodes (shift=8). NBUCK = CDIV(N,256) <= 512 (N <= 131072).

// per-block LDS histogram of dst>>8, one global atomic per (block,bucket)
__global__ __launch_bounds__(256) void k_bcount(
    const int* __restrict__ dst, int E, int nbuck, int* __restrict__ bcnt)
{
    __shared__ int cnt[512];
    const int t = threadIdx.x;
    for (int i = t; i < nbuck; i += 256) cnt[i] = 0;
    __syncthreads();
    const int e0 = blockIdx.x * 4096;
    #pragma unroll
    for (int q = 0; q < 16; ++q){
        int idx = e0 + q*256 + t;
        if (idx < E) atomicAdd(&cnt[dst[idx] >> 8], 1);
    }
    __syncthreads();
    for (int i = t; i < nbuck; i += 256){
        int c = cnt[i];
        if (c) atomicAdd(&bcnt[i], c);
    }
}

// single block: exclusive scan of bucket counts -> bbase, gcur
__global__ void k_bscan(const int* __restrict__ bcnt, int nbuck, int E,
                        int* __restrict__ bbase, int* __restrict__ gcur)
{
    __shared__ int s[512];
    int t = threadIdx.x;
    int v = (t < nbuck) ? bcnt[t] : 0;
    s[t] = v;
    __syncthreads();
    for (int off = 1; off < 512; off <<= 1){
        int x = (t >= off) ? s[t-off] : 0;
        __syncthreads();
        s[t] += x;
        __syncthreads();
    }
    if (t < nbuck){ int e = s[t] - v; bbase[t] = e; gcur[t] = e; }
    if (t == 0) bbase[nbuck] = E;
}

// pass A: scatter packed (ldst<<24 | src) into bucket regions
__global__ __launch_bounds__(256) void k_bucketA(
    const int* __restrict__ src, const int* __restrict__ dst, int E,
    int nbuck, int* __restrict__ gcur, uint* __restrict__ ebuf)
{
    __shared__ int cnt[512];
    __shared__ int base[512];
    const int t  = threadIdx.x;
    const int e0 = blockIdx.x * 4096;
    for (int i = t; i < nbuck; i += 256) cnt[i] = 0;
    __syncthreads();
    uint pk[16]; int mb[16];
    #pragma unroll
    for (int q = 0; q < 16; ++q){
        int idx = e0 + q*256 + t;
        int b = -1; uint pkv = 0;
        if (idx < E){
            int s = src[idx], d = dst[idx];
            b = d >> 8;
            pkv = (uint)s | ((uint)(d & 255) << 24);
            atomicAdd(&cnt[b], 1);
        }
        mb[q] = b; pk[q] = pkv;
    }
    __syncthreads();
    for (int i = t; i < nbuck; i += 256){
        int c = cnt[i];
        base[i] = c ? atomicAdd(&gcur[i], c) : 0;
    }
    __syncthreads();
    for (int i = t; i < nbuck; i += 256) cnt[i] = 0;
    __syncthreads();
    #pragma unroll
    for (int q = 0; q < 16; ++q){
        if (mb[q] >= 0){
            int b   = mb[q];
            int pos = base[b] + atomicAdd(&cnt[b], 1);
            ebuf[pos] = pk[q];
        }
    }
}

// pass B: one block per bucket -> local deg (LDS), local scan, row_ptr,
// inv_deg, and CSR col_idx fill. All atomics in LDS; global writes stay
// in the bucket's contiguous 16KB region.
__global__ __launch_bounds__(256) void k_build(
    const uint* __restrict__ ebuf, const int* __restrict__ bbase,
    int N, int E, int* __restrict__ row_ptr, float* __restrict__ inv_deg,
    int* __restrict__ col_idx)
{
    __shared__ int cnt[256];
    __shared__ int scn[256];
    const int b = blockIdx.x;
    const int t = threadIdx.x;
    const int n0 = b << 8;
    const int ebase = bbase[b], eend = bbase[b+1];

    cnt[t] = 0;
    __syncthreads();
    for (int j = ebase + t; j < eend; j += 256)
        atomicAdd(&cnt[ebuf[j] >> 24], 1);
    __syncthreads();

    int d = cnt[t];
    scn[t] = d;
    __syncthreads();
    for (int off = 1; off < 256; off <<= 1){
        int x = (t >= off) ? scn[t-off] : 0;
        __syncthreads();
        scn[t] += x;
        __syncthreads();
    }
    int excl = scn[t] - d;
    int node = n0 + t;
    if (node < N){
        row_ptr[node] = ebase + excl;
        inv_deg[node] = 1.0f / (float)(d > 1 ? d : 1);
    }
    if (b == 0 && t == 0) row_ptr[N] = E;

    cnt[t] = excl;   // reuse as cursor
    __syncthreads();
    for (int j = ebase + t; j < eend; j += 256){
        uint e = ebuf[j];
        int p = atomicAdd(&cnt[e >> 24], 1);
        col_idx[ebase + p] = (int)(e & 0xFFFFFFu);
    }
}

// ---------------------------------------------------------------- conversions
__global__ void k_cvt_x(const float* __restrict__ in, ushort* __restrict__ out, int n4){
    int i = blockIdx.x*blockDim.x + threadIdx.x;
    if (i >= n4) return;
    float4 v = reinterpret_cast<const float4*>(in)[i];
    ushort4 o; o.x=f2b(v.x); o.y=f2b(v.y); o.z=f2b(v.z); o.w=f2b(v.w);
    reinterpret_cast<ushort4*>(out)[i] = o;
}

// in: [nslab][K][C] f32 -> out: [nslab][C][K] bf16 (transposed per slab)
__global__ void k_cvt_t(const float* __restrict__ in, ushort* __restrict__ out,
                        int K, int C, int total){
    int i = blockIdx.x*blockDim.x + threadIdx.x;
    if (i >= total) return;
    int kc = K*C;
    int s = i / kc, r = i - s*kc;
    int k = r / C, c = r - k*C;
    out[s*kc + c*K + k] = f2b(in[i]);
}

// ---------------------------------------------------------------- aggregation (bf16)
__global__ __launch_bounds__(256) void k_agg_bf(
    const ushort* __restrict__ h, const int* __restrict__ row_ptr,
    const int* __restrict__ col_idx, const float* __restrict__ inv_deg,
    ushort* __restrict__ agg, int N)
{
    int node = (blockIdx.x*blockDim.x + threadIdx.x) >> 6;
    int lane = threadIdx.x & 63;
    if (node >= N) return;
    const int g = lane >> 4, l15 = lane & 15;
    const int beg = row_ptr[node], end = row_ptr[node+1];

    float a[8];
    #pragma unroll
    for (int q = 0; q < 8; ++q) a[q] = 0.f;

    int j = beg + g;
    while (j + 4 < end){
        int s0 = col_idx[j];
        int s1 = col_idx[j+4];
        uint4 v0 = *reinterpret_cast<const uint4*>(h + (size_t)s0*128 + l15*8);
        uint4 v1 = *reinterpret_cast<const uint4*>(h + (size_t)s1*128 + l15*8);
        uint w0[4] = {v0.x, v0.y, v0.z, v0.w};
        uint w1[4] = {v1.x, v1.y, v1.z, v1.w};
        #pragma unroll
        for (int q = 0; q < 4; ++q){
            a[2*q]   += b2f((ushort)(w0[q] & 0xffffu)) + b2f((ushort)(w1[q] & 0xffffu));
            a[2*q+1] += b2f((ushort)(w0[q] >> 16))     + b2f((ushort)(w1[q] >> 16));
        }
        j += 8;
    }
    if (j < end){
        int s0 = col_idx[j];
        uint4 v0 = *reinterpret_cast<const uint4*>(h + (size_t)s0*128 + l15*8);
        uint w0[4] = {v0.x, v0.y, v0.z, v0.w};
        #pragma unroll
        for (int q = 0; q < 4; ++q){
            a[2*q]   += b2f((ushort)(w0[q] & 0xffffu));
            a[2*q+1] += b2f((ushort)(w0[q] >> 16));
        }
    }

    #pragma unroll
    for (int q = 0; q < 8; ++q){
        a[q] += __shfl_xor(a[q], 16);
        a[q] += __shfl_xor(a[q], 32);
    }

    if (g == 0){
        float sc = inv_deg[node];
        uint r[4];
        #pragma unroll
        for (int q = 0; q < 4; ++q)
            r[q] = (uint)f2b(a[2*q]*sc) | ((uint)f2b(a[2*q+1]*sc) << 16);
        *reinterpret_cast<uint4*>(agg + (size_t)node*128 + l15*8) =
            make_uint4(r[0], r[1], r[2], r[3]);
    }
}

// ---------------------------------------------------------------- MFMA GEMM
template<int NCF, int STATS, int OUTBF>
__global__ __launch_bounds__(256) void k_gemm_mfma(
    const ushort* __restrict__ A0, const ushort* __restrict__ T0,
    const ushort* __restrict__ A1, const ushort* __restrict__ T1,
    const ushort* __restrict__ A2, const ushort* __restrict__ T2,
    const ushort* __restrict__ A3, const ushort* __restrict__ T3,
    int P, const float* __restrict__ bias,
    ushort* __restrict__ out_bf, float* __restrict__ out_f32,
    float* __restrict__ partials, int N)
{
    __shared__ ushort Ws[NCF*16*128];
    const int t   = threadIdx.x;
    const int w   = t >> 6, l = t & 63;
    const int l15 = l & 15, lg = l >> 4;
    const int r0   = blockIdx.x * 128;
    const int wrow = w * 32;

    f32x4 acc[2][NCF];
    #pragma unroll
    for (int i = 0; i < 2; ++i)
        #pragma unroll
        for (int j = 0; j < NCF; ++j) acc[i][j] = (f32x4){0.f,0.f,0.f,0.f};

    for (int p = 0; p < P; ++p){
        const ushort* A = (p==0)?A0:(p==1)?A1:(p==2)?A2:A3;
        const ushort* T = (p==0)?T0:(p==1)?T1:(p==2)?T2:T3;
        if (p) __syncthreads();
        #pragma unroll
        for (int q = 0; q < NCF; ++q){
            int lin  = q*256 + t;
            int row  = lin >> 4, c16 = lin & 15;
            int c16s = c16 ^ (row & 7);
            uint4 v = *reinterpret_cast<const uint4*>(T + (size_t)row*128 + c16*8);
            *reinterpret_cast<uint4*>(&Ws[row*128 + c16s*8]) = v;
        }
        __syncthreads();
        #pragma unroll
        for (int kk = 0; kk < 4; ++kk){
            const int k0 = kk*32;
            short8_t a[2];
            #pragma unroll
            for (int rf = 0; rf < 2; ++rf){
                size_t gr = (size_t)(r0 + wrow + rf*16 + l15);
                a[rf] = *reinterpret_cast<const short8_t*>(A + gr*128 + k0 + lg*8);
            }
            #pragma unroll
            for (int cf = 0; cf < NCF; ++cf){
                int row  = cf*16 + l15;
                int c16  = (k0 >> 3) + lg;
                int c16s = c16 ^ (row & 7);
                short8_t b = *reinterpret_cast<const short8_t*>(&Ws[row*128 + c16s*8]);
                acc[0][cf] = __builtin_amdgcn_mfma_f32_16x16x32_bf16(a[0], b, acc[0][cf], 0, 0, 0);
                acc[1][cf] = __builtin_amdgcn_mfma_f32_16x16x32_bf16(a[1], b, acc[1][cf], 0, 0, 0);
            }
        }
    }

    float bs[NCF];
    #pragma unroll
    for (int cf = 0; cf < NCF; ++cf) bs[cf] = bias[cf*16 + l15];

    float s1[NCF], s2[NCF];
    #pragma unroll
    for (int cf = 0; cf < NCF; ++cf){ s1[cf] = 0.f; s2[cf] = 0.f; }

    #pragma unroll
    for (int rf = 0; rf < 2; ++rf){
        #pragma unroll
        for (int q = 0; q < 4; ++q){
            int gr = r0 + wrow + rf*16 + lg*4 + q;
            bool valid = gr < N;
            #pragma unroll
            for (int cf = 0; cf < NCF; ++cf){
                float v = acc[rf][cf][q] + bs[cf];
                if (valid){
                    if (STATS){ s1[cf] += v; s2[cf] += v*v; }
                    int col = cf*16 + l15;
                    if (OUTBF) out_bf[(size_t)gr*(NCF*16) + col] = f2b(v);
                    else       out_f32[(size_t)gr*(NCF*16) + col] = v;
                }
            }
        }
    }
    if (STATS){
        #pragma unroll
        for (int cf = 0; cf < NCF; ++cf){
            s1[cf] += __shfl_xor(s1[cf], 16);
            s1[cf] += __shfl_xor(s1[cf], 32);
            s2[cf] += __shfl_xor(s2[cf], 16);
            s2[cf] += __shfl_xor(s2[cf], 32);
        }
        if (l < 16){
            float* pb = partials + (size_t)(blockIdx.x*4 + w)*256;
            #pragma unroll
            for (int cf = 0; cf < NCF; ++cf){
                pb[cf*16 + l15]       = s1[cf];
                pb[128 + cf*16 + l15] = s2[cf];
            }
        }
    }
}

// ---------------------------------------------------------------- BN reduce
__global__ void k_bnreduce(const float* __restrict__ partials, int I, int N,
                           const float* __restrict__ gamma, const float* __restrict__ beta,
                           float* __restrict__ ss)
{
    int c = blockIdx.x;
    int l = threadIdx.x;
    float s1 = 0.f, s2 = 0.f;
    for (int i = l; i < I; i += 64){
        s1 += partials[(size_t)i*256 + c];
        s2 += partials[(size_t)i*256 + 128 + c];
    }
    #pragma unroll
    for (int off = 32; off; off >>= 1){
        s1 += __shfl_xor(s1, off);
        s2 += __shfl_xor(s2, off);
    }
    if (l == 0){
        float m   = s1 / (float)N;
        float var = s2 / (float)N - m*m;
        float sc  = rsqrtf(var + 1e-5f) * gamma[c];
        ss[c]     = sc;
        ss[128+c] = beta[c] - m*sc;
    }
}

// ---------------------------------------------------------------- norm + act (bf16)
template<int LEAKY>
__global__ __launch_bounds__(256) void k_norm_act_bf(
    const ushort* __restrict__ pre, const float* __restrict__ ss,
    ushort* __restrict__ out, int total8)
{
    int i = blockIdx.x*blockDim.x + threadIdx.x;
    if (i >= total8) return;
    uint4 v = reinterpret_cast<const uint4*>(pre)[i];
    int c0 = (i & 15) * 8;
    uint vv[4] = {v.x, v.y, v.z, v.w};
    uint r[4];
    #pragma unroll
    for (int q = 0; q < 4; ++q){
        float f0 = b2f((ushort)(vv[q] & 0xffffu)) * ss[c0+q*2]   + ss[128+c0+q*2];
        float f1 = b2f((ushort)(vv[q] >> 16))     * ss[c0+q*2+1] + ss[128+c0+q*2+1];
        if (LEAKY){ f0 = f0 > 0.f ? f0 : 0.01f*f0; f1 = f1 > 0.f ? f1 : 0.01f*f1; }
        else      { f0 = fmaxf(f0, 0.f); f1 = fmaxf(f1, 0.f); }
        r[q] = (uint)f2b(f0) | ((uint)f2b(f1) << 16);
    }
    reinterpret_cast<uint4*>(out)[i] = make_uint4(r[0], r[1], r[2], r[3]);
}

// ---------------------------------------------------------------- launch
extern "C" void kernel_launch(void* const* d_in, const int* in_sizes, int n_in,
                              void* d_out, int out_size, void* d_ws, size_t ws_size,
                              hipStream_t stream)
{
    const float* x     = (const float*)d_in[0];
    const int*   ei    = (const int*)  d_in[1];
    const float* Wl    = (const float*)d_in[2];
    const float* bl    = (const float*)d_in[3];
    const float* Wr    = (const float*)d_in[4];
    const float* gamma = (const float*)d_in[5];
    const float* beta  = (const float*)d_in[6];
    const float* W1    = (const float*)d_in[7];
    const float* b1    = (const float*)d_in[8];
    const float* g1    = (const float*)d_in[9];
    const float* be1   = (const float*)d_in[10];
    const float* W2    = (const float*)d_in[11];
    const float* b2    = (const float*)d_in[12];
    float* out = (float*)d_out;

    const int N  = in_sizes[0] / 128;
    const int E  = in_sizes[1] / 2;
    const int NB = CDIV(N, 128);
    const size_t NPAD = (size_t)NB * 128;
    const int* src = ei;
    const int* dst = ei + E;

    const int NBUCK = CDIV(N, 256);   // <= 512 for N <= 131072

    char* w = (char*)d_ws;
    const size_t SB = NPAD * 128 * sizeof(ushort);
    ushort* x_bf = (ushort*)(w + 0*SB);
    ushort* h0   = (ushort*)(w + 1*SB);
    ushort* h1   = (ushort*)(w + 2*SB);
    ushort* h2   = (ushort*)(w + 3*SB);
    ushort* aggb = (ushort*)(w + 4*SB);
    ushort* preb = (ushort*)(w + 5*SB);
    char* p = w + 6*SB;
    ushort* WtL = (ushort*)p;  p += (size_t)3*16384*2;
    ushort* WtR = (ushort*)p;  p += (size_t)3*16384*2;
    ushort* Wt1 = (ushort*)p;  p += (size_t)4*16384*2;
    ushort* Wt2 = (ushort*)p;  p += (size_t)8192*2;
    float* partials = (float*)p; p += (size_t)NB*4*256*sizeof(float);
    uint*  ebuf     = (uint*)p;  p += (size_t)E*4;
    int*   col_idx  = (int*)p;   p += (size_t)E*4;
    int*   row_ptr  = (int*)p;   p += (size_t)(N+1)*4;
    float* inv_deg  = (float*)p; p += (size_t)N*4;
    int*   bcnt     = (int*)p;   p += 512*4;
    int*   bbase    = (int*)p;   p += 516*4;
    int*   gcur     = (int*)p;   p += 512*4;
    float* ssb      = (float*)p; p += 256*4;

    // conversions
    const int n4 = N * 32;
    k_cvt_x<<<CDIV(n4,256), 256, 0, stream>>>(x, x_bf, n4);
    k_cvt_t<<<CDIV(3*16384,256), 256, 0, stream>>>(Wl, WtL, 128, 128, 3*16384);
    k_cvt_t<<<CDIV(3*16384,256), 256, 0, stream>>>(Wr, WtR, 128, 128, 3*16384);
    k_cvt_t<<<CDIV(4*16384,256), 256, 0, stream>>>(W1, Wt1, 128, 128, 4*16384);
    k_cvt_t<<<CDIV(8192,256),    256, 0, stream>>>(W2, Wt2, 128,  64, 8192);

    // bucketed CSR build
    hipMemsetAsync(bcnt, 0, 512*4, stream);
    k_bcount<<<CDIV(E,4096), 256, 0, stream>>>(dst, E, NBUCK, bcnt);
    k_bscan<<<1, 512, 0, stream>>>(bcnt, NBUCK, E, bbase, gcur);
    k_bucketA<<<CDIV(E,4096), 256, 0, stream>>>(src, dst, E, NBUCK, gcur, ebuf);
    k_build<<<NBUCK, 256, 0, stream>>>(ebuf, bbase, N, E, row_ptr, inv_deg, col_idx);

    // 3 SAGE layers
    const ushort* h = x_bf;
    ushort* hb[3] = {h0, h1, h2};
    const int total8 = N * 16;
    for (int L = 0; L < 3; ++L){
        k_agg_bf<<<CDIV(N,4), 256, 0, stream>>>(h, row_ptr, col_idx, inv_deg, aggb, N);
        k_gemm_mfma<8,1,1><<<NB, 256, 0, stream>>>(
            aggb, WtL + (size_t)L*16384,
            h,    WtR + (size_t)L*16384,
            nullptr, nullptr, nullptr, nullptr,
            2, bl + (size_t)L*128, preb, nullptr, partials, N);
        k_bnreduce<<<128, 64, 0, stream>>>(partials, NB*4, N,
            gamma + (size_t)L*128, beta + (size_t)L*128, ssb);
        k_norm_act_bf<0><<<CDIV(total8,256), 256, 0, stream>>>(preb, ssb, hb[L], total8);
        h = hb[L];
    }

    // head
    k_gemm_mfma<8,1,1><<<NB, 256, 0, stream>>>(
        x_bf, Wt1 + 0,
        h0,   Wt1 + 16384,
        h1,   Wt1 + 2*16384,
        h2,   Wt1 + 3*16384,
        4, b1, preb, nullptr, partials, N);
    k_bnreduce<<<128, 64, 0, stream>>>(partials, NB*4, N, g1, be1, ssb);
    k_norm_act_bf<1><<<CDIV(total8,256), 256, 0, stream>>>(preb, ssb, aggb, total8);

    k_gemm_mfma<4,0,0><<<NB, 256, 0, stream>>>(
        aggb, Wt2, nullptr, nullptr, nullptr, nullptr, nullptr, nullptr,
        1, b2, nullptr, out, nullptr, N);
}